// Round 8
// baseline (23920.695 us; speedup 1.0000x reference)
//
#include <hip/hip_runtime.h>

typedef __attribute__((ext_vector_type(8))) short short8;
typedef __attribute__((ext_vector_type(4))) float f32x4;

constexpr int Bsz = 128;   // batch
constexpr int Tlen = 512;  // seq len
constexpr int Hd = 1024;   // hidden
constexpr int K0 = 1024;   // L0 ring K (h only; x handled via P table)
constexpr int K1 = 2048;   // L1 ring K = [h1 | y0]
constexpr int BK = 128;    // K-chunk

__device__ __forceinline__ unsigned short f2b(float f) {
  unsigned int u = __float_as_uint(f);
  u = (u + 0x7FFFu + ((u >> 16) & 1u)) >> 16;
  return (unsigned short)u;
}
__device__ __forceinline__ float b2f(unsigned short u) {
  return __uint_as_float(((unsigned int)u) << 16);
}

// ---------------- persistent kernel: all 513 rounds, grid barrier between ----------------
// 256 WGs: layer = wg>>7, mh = wg&1 (64 rows), c = (wg&127)>>1 (16 h-cols, 3 gates).
// grid=256, >=1 block/CU capacity (56KB LDS, <=256 VGPR) => all blocks co-resident
// => monotonic-counter barrier is deadlock-free.
__global__ void __launch_bounds__(256, 1) gru_persist(
    const int* __restrict__ src,
    const float* __restrict__ P,              // [512][3072] fp32: emb @ wih0^T + bih0
    const unsigned short* __restrict__ Whh0b, // [3072][1024] bf16
    const unsigned short* __restrict__ Whh1b, // [3072][1024] bf16
    const unsigned short* __restrict__ Wih1b, // [3072][1024] bf16
    const float* __restrict__ bhh0,
    const float* __restrict__ bih1,
    const float* __restrict__ bhh1,
    float* __restrict__ dout,
    unsigned short* __restrict__ A0,
    unsigned short* __restrict__ A1,
    unsigned int* __restrict__ bar)
{
  __shared__ __align__(16) unsigned char smem[57344];  // A:2x16KB, B:2x12KB; reduce aliases

  const int wg = blockIdx.x;
  const int layer = wg >> 7;
  const int mh = wg & 1;
  const int c = (wg & 127) >> 1;
  const int R0 = mh * 64;
  const int J0 = c * 16;

  const int Ksz = layer ? K1 : K0;
  const int nch = Ksz / BK;                 // 8 or 16
  unsigned short* Ab = layer ? A1 : A0;
  const unsigned short* Wh = layer ? Whh1b : Whh0b;
  const unsigned short* Wx = Wih1b;         // only used by L1 (k>=1024)

  const int tid = threadIdx.x;
  const int w = tid >> 6;       // wave 0..3 — K-segment owner
  const int lane = tid & 63;
  const int lrow = lane >> 4;   // quad
  const int lcol = lane & 15;

  const int col = J0 + lcol;
  const float* bhh = layer ? bhh1 : bhh0;
  const float bhr = bhh[col], bhz = bhh[1024 + col], bhn = bhh[2048 + col];
  const float bir = layer ? bih1[col] : 0.f;
  const float biz = layer ? bih1[1024 + col] : 0.f;
  const float bin = layer ? bih1[2048 + col] : 0.f;

  for (int r = 0; r <= 512; ++r) {
    const bool active = layer ? (r >= 1) : (r < 512);
    if (active) {
      const bool first = layer ? (r == 1) : (r == 0);
      const int par = r & 1;
      const unsigned short* Acur = Ab + par * (Bsz * Ksz);
      unsigned short* Anext = Ab + (par ^ 1) * (Bsz * Ksz);

      f32x4 ar[4], az[4], anh[4], anx[4];
#pragma unroll
      for (int f = 0; f < 4; ++f) {
        ar[f] = (f32x4){0.f, 0.f, 0.f, 0.f};
        az[f] = (f32x4){0.f, 0.f, 0.f, 0.f};
        anh[f] = (f32x4){0.f, 0.f, 0.f, 0.f};
        anx[f] = (f32x4){0.f, 0.f, 0.f, 0.f};
      }

      // first round: L0 skips everything (K all-h); L1 skips h chunks (0..7)
      const int ch0 = first ? (layer ? 8 : nch) : 0;

      if (ch0 < nch) {
        short8 pa[4], pb[3];
        auto ld = [&](int ch) {
          const int k0 = ch * BK;
#pragma unroll
          for (int s = 0; s < 4; ++s) {
            const int idx = tid + s * 256, rowi = idx >> 4, k8 = idx & 15;
            pa[s] = *(const short8*)(Acur + (R0 + rowi) * Ksz + k0 + k8 * 8);
          }
#pragma unroll
          for (int s = 0; s < 3; ++s) {
            const int idx = tid + s * 256, tr = idx >> 4, k8 = idx & 15;
            const int wrow = (tr >> 4) * 1024 + J0 + (tr & 15);
            const unsigned short* gp = (k0 < 1024)
                ? (Wh + wrow * 1024 + k0 + k8 * 8)
                : (Wx + wrow * 1024 + (k0 - 1024) + k8 * 8);
            pb[s] = *(const short8*)gp;
          }
        };
        auto st = [&](int b) {
          unsigned short* sA = (unsigned short*)(smem + b * 16384);
          unsigned short* sB = (unsigned short*)(smem + 32768 + b * 12288);
#pragma unroll
          for (int s = 0; s < 4; ++s) {
            const int idx = tid + s * 256, rowi = idx >> 4, k8 = idx & 15;
            *(short8*)(sA + rowi * BK + k8 * 8) = pa[s];
          }
#pragma unroll
          for (int s = 0; s < 3; ++s) {
            const int idx = tid + s * 256, tr = idx >> 4, k8 = idx & 15;
            *(short8*)(sB + tr * BK + k8 * 8) = pb[s];
          }
        };

        ld(ch0); st(0);
        __syncthreads();

        for (int ch = ch0; ch < nch; ++ch) {
          const int b = (ch - ch0) & 1;
          const bool pf = (ch + 1 < nch);
          if (pf) ld(ch + 1);                       // prefetch to regs

          const unsigned short* sA = (const unsigned short*)(smem + b * 16384);
          const unsigned short* sB = (const unsigned short*)(smem + 32768 + b * 12288);
          const int ke = w * 32 + lrow * 8;         // this wave's K-segment
          short8 bfr = *(const short8*)(sB + (lcol) * BK + ke);
          short8 bfz = *(const short8*)(sB + (16 + lcol) * BK + ke);
          short8 bfn = *(const short8*)(sB + (32 + lcol) * BK + ke);
          const bool hp = (ch * BK) < 1024;
#pragma unroll
          for (int f = 0; f < 4; ++f) {
            short8 a = *(const short8*)(sA + (f * 16 + lcol) * BK + ke);
            ar[f] = __builtin_amdgcn_mfma_f32_16x16x32_bf16(a, bfr, ar[f], 0, 0, 0);
            az[f] = __builtin_amdgcn_mfma_f32_16x16x32_bf16(a, bfz, az[f], 0, 0, 0);
            if (hp) anh[f] = __builtin_amdgcn_mfma_f32_16x16x32_bf16(a, bfn, anh[f], 0, 0, 0);
            else    anx[f] = __builtin_amdgcn_mfma_f32_16x16x32_bf16(a, bfn, anx[f], 0, 0, 0);
          }
          if (pf) st(b ^ 1);                        // write next chunk's buffer
          __syncthreads();
        }
      }

      // ---- cross-wave K reduction: waves 1..3 dump, wave 0 sums
      f32x4* red = (f32x4*)smem;                    // 48 KB, aliases staging buffers
      if (w > 0) {
        f32x4* dst = red + (w - 1) * 1024;
#pragma unroll
        for (int f = 0; f < 4; ++f) {
          dst[(0 * 4 + f) * 64 + lane] = ar[f];
          dst[(1 * 4 + f) * 64 + lane] = az[f];
          dst[(2 * 4 + f) * 64 + lane] = anh[f];
          dst[(3 * 4 + f) * 64 + lane] = anx[f];
        }
      }
      __syncthreads();
      if (w == 0) {
#pragma unroll
        for (int f = 0; f < 4; ++f) {
          ar[f]  += red[(0*4+f)*64+lane] + red[1024+(0*4+f)*64+lane] + red[2048+(0*4+f)*64+lane];
          az[f]  += red[(1*4+f)*64+lane] + red[1024+(1*4+f)*64+lane] + red[2048+(1*4+f)*64+lane];
          anh[f] += red[(2*4+f)*64+lane] + red[1024+(2*4+f)*64+lane] + red[2048+(2*4+f)*64+lane];
          anx[f] += red[(3*4+f)*64+lane] + red[1024+(3*4+f)*64+lane] + red[2048+(3*4+f)*64+lane];
        }

        const bool lastw = layer ? (r == 512) : (r == 511);
#pragma unroll
        for (int f = 0; f < 4; ++f) {
#pragma unroll
          for (int i = 0; i < 4; ++i) {
            const int row = R0 + f * 16 + lrow * 4 + i;
            float gr, gz, gn;                        // x-side additive
            if (layer == 0) {
              const int sv = src[row * Tlen + r];
              const float* pr = P + sv * 3072 + col;
              gr = pr[0]; gz = pr[1024]; gn = pr[2048];
            } else {
              gr = bir; gz = biz; gn = bin;
            }
            float rg = ar[f][i] + gr + bhr;
            rg = 1.f / (1.f + __expf(-rg));
            float zg = az[f][i] + gz + bhz;
            zg = 1.f / (1.f + __expf(-zg));
            const float ng = tanhf((anx[f][i] + gn) + rg * (anh[f][i] + bhn));
            const float hold = first ? 0.f : b2f(Acur[row * Ksz + col]);
            const float hnew = (1.f - zg) * ng + zg * hold;
            const unsigned short hb = f2b(hnew);
            Anext[row * Ksz + col] = hb;
            if (layer == 0) A1[(par ^ 1) * (Bsz * K1) + row * K1 + 1024 + col] = hb;
            if (lastw) dout[layer * (Bsz * Hd) + row * Hd + col] = hnew;
          }
        }
      }
    }

    // ---- grid barrier (device-scope, monotonic counter; all blocks co-resident)
    __syncthreads();                 // wave 0's global writes done before arrival
    if (tid == 0) {
      __hip_atomic_fetch_add(bar, 1u, __ATOMIC_RELEASE, __HIP_MEMORY_SCOPE_AGENT);
      const unsigned tgt = 256u * (unsigned)(r + 1);
      while (__hip_atomic_load(bar, __ATOMIC_ACQUIRE, __HIP_MEMORY_SCOPE_AGENT) < tgt)
        __builtin_amdgcn_s_sleep(1);
    }
    __syncthreads();
  }
}

// ---------------- prep: fp32 -> bf16 weight convert ----------------
__global__ void __launch_bounds__(256) cvt_k(const float* __restrict__ s,
                                            unsigned short* __restrict__ d, int n) {
  const int i = (blockIdx.x * 256 + threadIdx.x) * 8;
  if (i >= n) return;
  const float4 a = *(const float4*)(s + i);
  const float4 b = *(const float4*)(s + i + 4);
  short8 o;
  o[0] = (short)f2b(a.x); o[1] = (short)f2b(a.y);
  o[2] = (short)f2b(a.z); o[3] = (short)f2b(a.w);
  o[4] = (short)f2b(b.x); o[5] = (short)f2b(b.y);
  o[6] = (short)f2b(b.z); o[7] = (short)f2b(b.w);
  *(short8*)(d + i) = o;
}

// ---------------- prep: P = emb @ wih0^T + bih0 (fp32, exact path) ----------------
__global__ void __launch_bounds__(256) pemb_k(const float* __restrict__ emb,
                                             const float* __restrict__ wih0,
                                             const float* __restrict__ bih0,
                                             float* __restrict__ P) {
  __shared__ float se[64 * 64];  // emb tile [vv][kk]
  const int g = blockIdx.x * 256 + threadIdx.x;
  const int v0 = blockIdx.y * 64;
  float acc[64];
#pragma unroll
  for (int i = 0; i < 64; ++i) acc[i] = 0.f;
  for (int kb = 0; kb < 8; ++kb) {
    __syncthreads();
#pragma unroll
    for (int s = 0; s < 4; ++s) {
      const int idx = threadIdx.x + s * 256;
      const int vv = idx >> 4, k4 = (idx & 15) * 4;
      *(float4*)(se + vv * 64 + k4) =
          *(const float4*)(emb + (v0 + vv) * 512 + kb * 64 + k4);
    }
    __syncthreads();
    float4 wv[16];
#pragma unroll
    for (int j = 0; j < 16; ++j)
      wv[j] = *(const float4*)(wih0 + g * 512 + kb * 64 + j * 4);
    for (int vv = 0; vv < 64; ++vv) {
      const float* er = se + vv * 64;
      float s0 = acc[vv];
#pragma unroll
      for (int j = 0; j < 16; ++j) {
        const float4 e = *(const float4*)(er + j * 4);
        s0 += wv[j].x * e.x + wv[j].y * e.y + wv[j].z * e.z + wv[j].w * e.w;
      }
      acc[vv] = s0;
    }
  }
  const float bb = bih0[g];
  for (int vv = 0; vv < 64; ++vv) P[(v0 + vv) * 3072 + g] = acc[vv] + bb;
}

__global__ void zero_bar(unsigned int* bar) {
  if (threadIdx.x == 0 && blockIdx.x == 0) *bar = 0u;
}

extern "C" void kernel_launch(void* const* d_in, const int* in_sizes, int n_in,
                              void* d_out, int out_size, void* d_ws, size_t ws_size,
                              hipStream_t stream) {
  const int* src = (const int*)d_in[0];
  const float* emb = (const float*)d_in[1];
  const float* wih0 = (const float*)d_in[2];
  const float* whh0 = (const float*)d_in[3];
  const float* bih0 = (const float*)d_in[4];
  const float* bhh0 = (const float*)d_in[5];
  const float* wih1 = (const float*)d_in[6];
  const float* whh1 = (const float*)d_in[7];
  const float* bih1 = (const float*)d_in[8];
  const float* bhh1 = (const float*)d_in[9];
  float* dout = (float*)d_out;

  char* p = (char*)d_ws;
  unsigned short* A0 = (unsigned short*)p;                       // 524288 B
  unsigned short* A1 = (unsigned short*)(p + 524288);            // 1048576 B
  unsigned short* Whh0b = (unsigned short*)(p + 1572864);        // 6291456 B
  unsigned short* Whh1b = (unsigned short*)(p + 7864320);        // 6291456 B
  unsigned short* Wih1b = (unsigned short*)(p + 14155776);       // 6291456 B
  float* P = (float*)(p + 20447232);                             // 6291456 B
  unsigned int* bar = (unsigned int*)(p + 26738688);             // 4 B
  // total ws use: 26738692 B (~25.5 MB)

  constexpr int NW = 3072 * 1024;  // elements per weight matrix
  hipLaunchKernelGGL(cvt_k, dim3(NW / (256 * 8)), dim3(256), 0, stream, whh0, Whh0b, NW);
  hipLaunchKernelGGL(cvt_k, dim3(NW / (256 * 8)), dim3(256), 0, stream, whh1, Whh1b, NW);
  hipLaunchKernelGGL(cvt_k, dim3(NW / (256 * 8)), dim3(256), 0, stream, wih1, Wih1b, NW);
  hipLaunchKernelGGL(pemb_k, dim3(12, 8), dim3(256), 0, stream, emb, wih0, bih0, P);
  hipLaunchKernelGGL(zero_bar, dim3(1), dim3(64), 0, stream, bar);

  hipLaunchKernelGGL(gru_persist, dim3(256), dim3(256), 0, stream,
                     src, P, Whh0b, Whh1b, Wih1b, bhh0, bih1, bhh1,
                     dout, A0, A1, bar);
}

// Round 9
// 13940.218 us; speedup vs baseline: 1.7159x; 1.7159x over previous
//
#include <hip/hip_runtime.h>

typedef __attribute__((ext_vector_type(8))) short short8;
typedef __attribute__((ext_vector_type(4))) float f32x4;

constexpr int Bsz = 128;   // batch
constexpr int Tlen = 512;  // seq len
constexpr int Hd = 1024;   // hidden
constexpr int K0 = 1024;   // L0 ring K (h only; x handled via P table)
constexpr int K1 = 2048;   // L1 ring K = [h1 | y0]
constexpr int BK = 128;    // K-chunk
constexpr int BKP = 136;   // LDS row stride (+8 elts = 16B: 68 dwords % 32 = 4 -> 2-way max, free)

__device__ __forceinline__ unsigned short f2b(float f) {
  unsigned int u = __float_as_uint(f);
  u = (u + 0x7FFFu + ((u >> 16) & 1u)) >> 16;
  return (unsigned short)u;
}
__device__ __forceinline__ float b2f(unsigned short u) {
  return __uint_as_float(((unsigned int)u) << 16);
}

// LDS layout (padded): A: 2 x 64*136 elts = 2x17408 B; B: 2 x 48*136 = 2x13056 B. total 60928 B.
// reduce region (48 KB) aliases the staging buffers.
constexpr int SM_A = 64 * BKP * 2;       // bytes per A buffer = 17408
constexpr int SM_B = 48 * BKP * 2;       // bytes per B buffer = 13056
constexpr int SM_TOT = 2 * SM_A + 2 * SM_B;

__global__ void __launch_bounds__(256, 1) gru_step(
    const int* __restrict__ src,
    const float* __restrict__ P,              // [512][3072] fp32: emb @ wih0^T + bih0
    const unsigned short* __restrict__ Whh0b, // [3072][1024] bf16
    const unsigned short* __restrict__ Whh1b, // [3072][1024] bf16
    const unsigned short* __restrict__ Wih1b, // [3072][1024] bf16
    const float* __restrict__ bhh0,
    const float* __restrict__ bih1,
    const float* __restrict__ bhh1,
    float* __restrict__ dout,
    unsigned short* __restrict__ A0,
    unsigned short* __restrict__ A1,
    int r)
{
  __shared__ __align__(16) unsigned char smem[SM_TOT];

  const int wg = blockIdx.x;
  const int layer = wg >> 7;
  const bool active = layer ? (r >= 1) : (r < 512);
  if (!active) return;

  const int mh = wg & 1;
  const int c = (wg & 127) >> 1;
  const int R0 = mh * 64;
  const int J0 = c * 16;

  const int Ksz = layer ? K1 : K0;
  const int nch = Ksz / BK;                 // 8 or 16
  unsigned short* Ab = layer ? A1 : A0;
  const unsigned short* Wh = layer ? Whh1b : Whh0b;
  const unsigned short* Wx = Wih1b;         // only used by L1 (k>=1024)
  const bool first = layer ? (r == 1) : (r == 0);

  const int tid = threadIdx.x;
  const int w = tid >> 6;       // wave 0..3 — K-segment owner
  const int lane = tid & 63;
  const int lrow = lane >> 4;   // quad
  const int lcol = lane & 15;

  const int par = r & 1;
  const unsigned short* Acur = Ab + par * (Bsz * Ksz);
  unsigned short* Anext = Ab + (par ^ 1) * (Bsz * Ksz);

  const int col = J0 + lcol;
  const float* bhh = layer ? bhh1 : bhh0;
  const float bhr = bhh[col], bhz = bhh[1024 + col], bhn = bhh[2048 + col];
  const float bir = layer ? bih1[col] : 0.f;
  const float biz = layer ? bih1[1024 + col] : 0.f;
  const float bin = layer ? bih1[2048 + col] : 0.f;

  // ---- epilogue-operand prefetch (wave 0 only): issue BEFORE the GEMM so the
  // ~0.4-1us of scattered-load latency hides under the K-loop.
  float gpr[4][4], gpz[4][4], gpn[4][4], ghold[4][4];
  if (w == 0) {
#pragma unroll
    for (int f = 0; f < 4; ++f) {
#pragma unroll
      for (int i = 0; i < 4; ++i) {
        const int row = R0 + f * 16 + lrow * 4 + i;
        if (layer == 0) {
          const int sv = src[row * Tlen + r];
          const float* pr = P + sv * 3072 + col;
          gpr[f][i] = pr[0]; gpz[f][i] = pr[1024]; gpn[f][i] = pr[2048];
        } else {
          gpr[f][i] = bir; gpz[f][i] = biz; gpn[f][i] = bin;
        }
        ghold[f][i] = first ? 0.f : b2f(Acur[row * Ksz + col]);
      }
    }
  }

  f32x4 ar[4], az[4], anh[4], anx[4];
#pragma unroll
  for (int f = 0; f < 4; ++f) {
    ar[f] = (f32x4){0.f, 0.f, 0.f, 0.f};
    az[f] = (f32x4){0.f, 0.f, 0.f, 0.f};
    anh[f] = (f32x4){0.f, 0.f, 0.f, 0.f};
    anx[f] = (f32x4){0.f, 0.f, 0.f, 0.f};
  }

  // first round: L0 skips everything (K all-h); L1 skips h chunks (0..7)
  const int ch0 = first ? (layer ? 8 : nch) : 0;

  if (ch0 < nch) {
    short8 pa[4], pb[3];
    auto ld = [&](int ch) {
      const int k0 = ch * BK;
#pragma unroll
      for (int s = 0; s < 4; ++s) {
        const int idx = tid + s * 256, rowi = idx >> 4, k8 = idx & 15;
        pa[s] = *(const short8*)(Acur + (R0 + rowi) * Ksz + k0 + k8 * 8);
      }
#pragma unroll
      for (int s = 0; s < 3; ++s) {
        const int idx = tid + s * 256, tr = idx >> 4, k8 = idx & 15;
        const int wrow = (tr >> 4) * 1024 + J0 + (tr & 15);
        const unsigned short* gp = (k0 < 1024)
            ? (Wh + wrow * 1024 + k0 + k8 * 8)
            : (Wx + wrow * 1024 + (k0 - 1024) + k8 * 8);
        pb[s] = *(const short8*)gp;
      }
    };
    auto st = [&](int b) {
      unsigned short* sA = (unsigned short*)(smem + b * SM_A);
      unsigned short* sB = (unsigned short*)(smem + 2 * SM_A + b * SM_B);
#pragma unroll
      for (int s = 0; s < 4; ++s) {
        const int idx = tid + s * 256, rowi = idx >> 4, k8 = idx & 15;
        *(short8*)(sA + rowi * BKP + k8 * 8) = pa[s];
      }
#pragma unroll
      for (int s = 0; s < 3; ++s) {
        const int idx = tid + s * 256, tr = idx >> 4, k8 = idx & 15;
        *(short8*)(sB + tr * BKP + k8 * 8) = pb[s];
      }
    };

    ld(ch0); st(0);
    __syncthreads();

    for (int ch = ch0; ch < nch; ++ch) {
      const int b = (ch - ch0) & 1;
      const bool pf = (ch + 1 < nch);
      if (pf) ld(ch + 1);                       // prefetch to regs

      const unsigned short* sA = (const unsigned short*)(smem + b * SM_A);
      const unsigned short* sB = (const unsigned short*)(smem + 2 * SM_A + b * SM_B);
      const int ke = w * 32 + lrow * 8;         // this wave's K-segment
      short8 bfr = *(const short8*)(sB + (lcol) * BKP + ke);
      short8 bfz = *(const short8*)(sB + (16 + lcol) * BKP + ke);
      short8 bfn = *(const short8*)(sB + (32 + lcol) * BKP + ke);
      const bool hp = (ch * BK) < 1024;
#pragma unroll
      for (int f = 0; f < 4; ++f) {
        short8 a = *(const short8*)(sA + (f * 16 + lcol) * BKP + ke);
        ar[f] = __builtin_amdgcn_mfma_f32_16x16x32_bf16(a, bfr, ar[f], 0, 0, 0);
        az[f] = __builtin_amdgcn_mfma_f32_16x16x32_bf16(a, bfz, az[f], 0, 0, 0);
        if (hp) anh[f] = __builtin_amdgcn_mfma_f32_16x16x32_bf16(a, bfn, anh[f], 0, 0, 0);
        else    anx[f] = __builtin_amdgcn_mfma_f32_16x16x32_bf16(a, bfn, anx[f], 0, 0, 0);
      }
      if (pf) st(b ^ 1);                        // write next chunk's buffer
      __syncthreads();
    }
  }

  // ---- cross-wave K reduction: waves 1..3 dump, wave 0 sums (48 KB, aliases staging)
  f32x4* red = (f32x4*)smem;
  if (w > 0) {
    f32x4* dst = red + (w - 1) * 1024;
#pragma unroll
    for (int f = 0; f < 4; ++f) {
      dst[(0 * 4 + f) * 64 + lane] = ar[f];
      dst[(1 * 4 + f) * 64 + lane] = az[f];
      dst[(2 * 4 + f) * 64 + lane] = anh[f];
      dst[(3 * 4 + f) * 64 + lane] = anx[f];
    }
  }
  __syncthreads();
  if (w == 0) {
#pragma unroll
    for (int f = 0; f < 4; ++f) {
      ar[f]  += red[(0*4+f)*64+lane] + red[1024+(0*4+f)*64+lane] + red[2048+(0*4+f)*64+lane];
      az[f]  += red[(1*4+f)*64+lane] + red[1024+(1*4+f)*64+lane] + red[2048+(1*4+f)*64+lane];
      anh[f] += red[(2*4+f)*64+lane] + red[1024+(2*4+f)*64+lane] + red[2048+(2*4+f)*64+lane];
      anx[f] += red[(3*4+f)*64+lane] + red[1024+(3*4+f)*64+lane] + red[2048+(3*4+f)*64+lane];
    }

    const bool lastw = layer ? (r == 512) : (r == 511);
#pragma unroll
    for (int f = 0; f < 4; ++f) {
#pragma unroll
      for (int i = 0; i < 4; ++i) {
        const int row = R0 + f * 16 + lrow * 4 + i;
        float rg = ar[f][i] + gpr[f][i] + bhr;
        rg = 1.f / (1.f + __expf(-rg));
        float zg = az[f][i] + gpz[f][i] + bhz;
        zg = 1.f / (1.f + __expf(-zg));
        const float ng = tanhf((anx[f][i] + gpn[f][i]) + rg * (anh[f][i] + bhn));
        const float hnew = (1.f - zg) * ng + zg * ghold[f][i];
        const unsigned short hb = f2b(hnew);
        Anext[row * Ksz + col] = hb;
        if (layer == 0) A1[(par ^ 1) * (Bsz * K1) + row * K1 + 1024 + col] = hb;
        if (lastw) dout[layer * (Bsz * Hd) + row * Hd + col] = hnew;
      }
    }
  }
}

// ---------------- prep: fp32 -> bf16 weight convert ----------------
__global__ void __launch_bounds__(256) cvt_k(const float* __restrict__ s,
                                            unsigned short* __restrict__ d, int n) {
  const int i = (blockIdx.x * 256 + threadIdx.x) * 8;
  if (i >= n) return;
  const float4 a = *(const float4*)(s + i);
  const float4 b = *(const float4*)(s + i + 4);
  short8 o;
  o[0] = (short)f2b(a.x); o[1] = (short)f2b(a.y);
  o[2] = (short)f2b(a.z); o[3] = (short)f2b(a.w);
  o[4] = (short)f2b(b.x); o[5] = (short)f2b(b.y);
  o[6] = (short)f2b(b.z); o[7] = (short)f2b(b.w);
  *(short8*)(d + i) = o;
}

// ---------------- prep: P = emb @ wih0^T + bih0 (fp32, exact path) ----------------
__global__ void __launch_bounds__(256) pemb_k(const float* __restrict__ emb,
                                             const float* __restrict__ wih0,
                                             const float* __restrict__ bih0,
                                             float* __restrict__ P) {
  __shared__ float se[64 * 64];  // emb tile [vv][kk]
  const int g = blockIdx.x * 256 + threadIdx.x;
  const int v0 = blockIdx.y * 64;
  float acc[64];
#pragma unroll
  for (int i = 0; i < 64; ++i) acc[i] = 0.f;
  for (int kb = 0; kb < 8; ++kb) {
    __syncthreads();
#pragma unroll
    for (int s = 0; s < 4; ++s) {
      const int idx = threadIdx.x + s * 256;
      const int vv = idx >> 4, k4 = (idx & 15) * 4;
      *(float4*)(se + vv * 64 + k4) =
          *(const float4*)(emb + (v0 + vv) * 512 + kb * 64 + k4);
    }
    __syncthreads();
    float4 wv[16];
#pragma unroll
    for (int j = 0; j < 16; ++j)
      wv[j] = *(const float4*)(wih0 + g * 512 + kb * 64 + j * 4);
    for (int vv = 0; vv < 64; ++vv) {
      const float* er = se + vv * 64;
      float s0 = acc[vv];
#pragma unroll
      for (int j = 0; j < 16; ++j) {
        const float4 e = *(const float4*)(er + j * 4);
        s0 += wv[j].x * e.x + wv[j].y * e.y + wv[j].z * e.z + wv[j].w * e.w;
      }
      acc[vv] = s0;
    }
  }
  const float bb = bih0[g];
  for (int vv = 0; vv < 64; ++vv) P[(v0 + vv) * 3072 + g] = acc[vv] + bb;
}

extern "C" void kernel_launch(void* const* d_in, const int* in_sizes, int n_in,
                              void* d_out, int out_size, void* d_ws, size_t ws_size,
                              hipStream_t stream) {
  const int* src = (const int*)d_in[0];
  const float* emb = (const float*)d_in[1];
  const float* wih0 = (const float*)d_in[2];
  const float* whh0 = (const float*)d_in[3];
  const float* bih0 = (const float*)d_in[4];
  const float* bhh0 = (const float*)d_in[5];
  const float* wih1 = (const float*)d_in[6];
  const float* whh1 = (const float*)d_in[7];
  const float* bih1 = (const float*)d_in[8];
  const float* bhh1 = (const float*)d_in[9];
  float* dout = (float*)d_out;

  char* p = (char*)d_ws;
  unsigned short* A0 = (unsigned short*)p;                       // 524288 B
  unsigned short* A1 = (unsigned short*)(p + 524288);            // 1048576 B
  unsigned short* Whh0b = (unsigned short*)(p + 1572864);        // 6291456 B
  unsigned short* Whh1b = (unsigned short*)(p + 7864320);        // 6291456 B
  unsigned short* Wih1b = (unsigned short*)(p + 14155776);       // 6291456 B
  float* P = (float*)(p + 20447232);                             // 6291456 B
  // total ws use: 26738688 B (~25.5 MB)

  constexpr int NW = 3072 * 1024;  // elements per weight matrix
  hipLaunchKernelGGL(cvt_k, dim3(NW / (256 * 8)), dim3(256), 0, stream, whh0, Whh0b, NW);
  hipLaunchKernelGGL(cvt_k, dim3(NW / (256 * 8)), dim3(256), 0, stream, whh1, Whh1b, NW);
  hipLaunchKernelGGL(cvt_k, dim3(NW / (256 * 8)), dim3(256), 0, stream, wih1, Wih1b, NW);
  hipLaunchKernelGGL(pemb_k, dim3(12, 8), dim3(256), 0, stream, emb, wih0, bih0, P);

  for (int r = 0; r < 513; ++r) {
    hipLaunchKernelGGL(gru_step, dim3(256), dim3(256), 0, stream,
                       src, P, Whh0b, Whh1b, Wih1b, bhh0, bih1, bhh1,
                       dout, A0, A1, r);
  }
}